// Round 4
// baseline (34.028 us; speedup 1.0000x reference)
//
#include <hip/hip_runtime.h>
#include <hip/hip_fp16.h>
#include <math.h>

#define NPOS 16384
#define NTOT 491520
#define NFEAT 768
#define DUMMY 768   // extra zero row in W1Th

typedef _Float16 h2 __attribute__((ext_vector_type(2)));

__device__ __forceinline__ int imin(int a, int b) { return a < b ? a : b; }
__device__ __forceinline__ float clamp01(float x) { return fminf(fmaxf(x, 0.f), 1.f); }

#if __has_builtin(__builtin_amdgcn_fdot2)
#define FDOT2(a, b, c) __builtin_amdgcn_fdot2((a), (b), (c), false)
#else
#define FDOT2(a, b, c) ((c) + (float)(a)[0] * (float)(b)[0] + (float)(a)[1] * (float)(b)[1])
#endif

__device__ __forceinline__ h2 toh2(__half2 x) { return __builtin_bit_cast(h2, x); }

// ---------------- prep kernel ----------------
// blocks 0..11  : W1 [64][768] f32 -> W1Th [769][64] fp16 (row f = 128B)
// block  12     : W2 [32][128] f32 -> W2T [64][32] half2 + zero row 768 of W1Th
// blocks 13..76 : white segment starts (linear scatter, neighbor via shfl_up)
// blocks 77..140: black segment starts
__global__ __launch_bounds__(256) void k_prep(
    const float* __restrict__ W1, const float* __restrict__ W2,
    const int* __restrict__ wi, const int* __restrict__ bi,
    __half* __restrict__ W1Th, __half2* __restrict__ W2T,
    int* __restrict__ wstart, int* __restrict__ bstart)
{
    __shared__ float tile[64][65];
    int bid = blockIdx.x, tid = threadIdx.x;
    if (bid < 12) {
        int f0 = bid * 64;
        int j = tid & 63, r0 = tid >> 6;
        for (int r = r0; r < 64; r += 4)
            tile[r][j] = W1[r * NFEAT + f0 + j];
        __syncthreads();
        int c = tid & 63, j0 = tid >> 6;
        for (int jj = j0; jj < 64; jj += 4)
            W1Th[(f0 + jj) * 64 + c] = __float2half(tile[c][jj]);
    } else if (bid == 12) {
        for (int x = tid; x < 64 * 32; x += 256) {
            int i = x >> 5, k = x & 31;
            W2T[x] = __floats2half2_rn(W2[k * 128 + 2 * i], W2[k * 128 + 2 * i + 1]);
        }
        if (tid < 64) W1Th[DUMMY * 64 + tid] = __float2half(0.f);
    } else if (bid < 77) {
        int lane = tid & 63;
        for (int t = (bid - 13) * 256 + tid; t < NTOT; t += 64 * 256) {
            int v = wi[t];
            int p = __shfl_up(v, 1);
            if (lane == 0) p = (t == 0) ? -1 : wi[t - 1];
            for (int b = p + 1; b <= v; ++b) wstart[b] = t;
            if (t == NTOT - 1)
                for (int b = v + 1; b <= NPOS; ++b) wstart[b] = NTOT;
        }
    } else {
        int lane = tid & 63;
        for (int t = (bid - 77) * 256 + tid; t < NTOT; t += 64 * 256) {
            int v = bi[t];
            int p = __shfl_up(v, 1);
            if (lane == 0) p = (t == 0) ? -1 : bi[t - 1];
            for (int b = p + 1; b <= v; ++b) bstart[b] = t;
            if (t == NTOT - 1)
                for (int b = v + 1; b <= NPOS; ++b) bstart[b] = NTOT;
        }
    }
}

// ---------------- fused gather + head ----------------
// One wave per position, NO block-wide barriers (all LDS traffic is wave-local).
// Gather: 64-row LDS index windows, 16 rows per unrolled chunk (4 ds_read broadcasts
// + 4 independent 8B row loads), dummy-row padded -> branch-free body.
// Head: a1 staged in wave-local LDS, 32 v_dot2 per lane + shuffle reduces.
__global__ __launch_bounds__(256) void k_fused(
    const int* __restrict__ wf, const int* __restrict__ bf,
    const uint2* __restrict__ W1q,      // [769][16] uint2 (fp16 rows, 128B)
    const __half2* __restrict__ W2T,    // [64][32] half2
    const int* __restrict__ wstart, const int* __restrict__ bstart,
    const float4* __restrict__ b1q,     // b1 as 16 float4
    const float* __restrict__ b2, const float* __restrict__ W3,
    const float* __restrict__ b3, float* __restrict__ out)
{
    __shared__ int ivs[4][64];
    __shared__ __half2 a1s[4][64];      // 128 halfs per wave

    int tid = threadIdx.x;
    int wave = tid >> 6, lane = tid & 63;
    int pos = blockIdx.x * 4 + wave;
    int g = lane >> 4, k = lane & 15;

    int ws_ = wstart[pos], we = wstart[pos + 1];
    int bs_ = bstart[pos], be = bstart[pos + 1];

    // prefetch first index chunk of BOTH colors (black latency hides under white compute)
    int wpre = (ws_ + lane < we) ? wf[ws_ + lane] : DUMMY;
    int bpre = (bs_ + lane < be) ? bf[bs_ + lane] : DUMMY;

    int* myiv = &ivs[wave][0];

    float wa0 = 0.f, wa1 = 0.f, wa2 = 0.f, wa3 = 0.f;
    float ba0 = 0.f, ba1 = 0.f, ba2 = 0.f, ba3 = 0.f;

    auto run = [&](const int* __restrict__ feats, int s, int e, int pre,
                   float& A0, float& A1, float& A2, float& A3) {
        for (int t = s; t < e; t += 64) {
            int v = (t == s) ? pre : ((t + lane < e) ? feats[t + lane] : DUMMY);
            myiv[lane] = v;                       // wave-local: no barrier needed
            int nc = (imin(e - t, 64) + 15) >> 4; // 16-row chunks (dummy-padded)
            for (int c = 0; c < nc; ++c) {
                int base = c * 16 + g;
                int f0 = myiv[base];
                int f1 = myiv[base + 4];
                int f2 = myiv[base + 8];
                int f3 = myiv[base + 12];
                uint2 d0 = W1q[f0 * 16 + k];      // 4 independent 8B loads in flight
                uint2 d1 = W1q[f1 * 16 + k];
                uint2 d2 = W1q[f2 * 16 + k];
                uint2 d3 = W1q[f3 * 16 + k];
                h2 l0 = __builtin_bit_cast(h2, d0.x), h0 = __builtin_bit_cast(h2, d0.y);
                h2 l1 = __builtin_bit_cast(h2, d1.x), h1 = __builtin_bit_cast(h2, d1.y);
                h2 l2 = __builtin_bit_cast(h2, d2.x), h21 = __builtin_bit_cast(h2, d2.y);
                h2 l3 = __builtin_bit_cast(h2, d3.x), h31 = __builtin_bit_cast(h2, d3.y);
                A0 += (float)l0[0] + (float)l1[0] + (float)l2[0] + (float)l3[0];
                A1 += (float)l0[1] + (float)l1[1] + (float)l2[1] + (float)l3[1];
                A2 += (float)h0[0] + (float)h1[0] + (float)h21[0] + (float)h31[0];
                A3 += (float)h0[1] + (float)h1[1] + (float)h21[1] + (float)h31[1];
            }
        }
    };

    run(wf, ws_, we, wpre, wa0, wa1, wa2, wa3);
    run(bf, bs_, be, bpre, ba0, ba1, ba2, ba3);

    // reduce across the 4 lane-groups (xor 16, 32)
    wa0 += __shfl_xor(wa0, 16); wa0 += __shfl_xor(wa0, 32);
    wa1 += __shfl_xor(wa1, 16); wa1 += __shfl_xor(wa1, 32);
    wa2 += __shfl_xor(wa2, 16); wa2 += __shfl_xor(wa2, 32);
    wa3 += __shfl_xor(wa3, 16); wa3 += __shfl_xor(wa3, 32);
    ba0 += __shfl_xor(ba0, 16); ba0 += __shfl_xor(ba0, 32);
    ba1 += __shfl_xor(ba1, 16); ba1 += __shfl_xor(ba1, 32);
    ba2 += __shfl_xor(ba2, 16); ba2 += __shfl_xor(ba2, 32);
    ba3 += __shfl_xor(ba3, 16); ba3 += __shfl_xor(ba3, 32);

    // bias + hardtanh + pack to fp16, stage a1 row (128 halfs) in wave-local LDS
    float4 bb = b1q[k];
    if (lane < 32) {
        __half2 p0, p1;
        if (g == 0) {
            p0 = __floats2half2_rn(clamp01(wa0 + bb.x), clamp01(wa1 + bb.y));
            p1 = __floats2half2_rn(clamp01(wa2 + bb.z), clamp01(wa3 + bb.w));
        } else {
            p0 = __floats2half2_rn(clamp01(ba0 + bb.x), clamp01(ba1 + bb.y));
            p1 = __floats2half2_rn(clamp01(ba2 + bb.z), clamp01(ba3 + bb.w));
        }
        a1s[wave][g * 32 + k * 2]     = p0;
        a1s[wave][g * 32 + k * 2 + 1] = p1;
    }
    // same-wave LDS write->read: compiler-inserted lgkmcnt wait, no barrier

    // head: lane = (j = output 0..31, h = i-half); 32 fdot2 each
    int j = lane & 31, h = lane >> 5;
    const __half2* a1row = &a1s[wave][h * 32];
    const __half2* wrow = W2T + h * 32 * 32 + j;
    float acc = 0.f;
#pragma unroll
    for (int t = 0; t < 32; ++t)
        acc = FDOT2(toh2(a1row[t]), toh2(wrow[t * 32]), acc);
    acc += __shfl_xor(acc, 32);

    float a2v = clamp01(acc + b2[j]);
    float p = a2v * W3[j];
    p += __shfl_xor(p, 16);
    p += __shfl_xor(p, 8);
    p += __shfl_xor(p, 4);
    p += __shfl_xor(p, 2);
    p += __shfl_xor(p, 1);
    if (lane == 0) {
        float x = p + b3[0];
        out[pos] = 1.f / (1.f + __expf(-x));
    }
}

extern "C" void kernel_launch(void* const* d_in, const int* in_sizes, int n_in,
                              void* d_out, int out_size, void* d_ws, size_t ws_size,
                              hipStream_t stream) {
    const int*   wf = (const int*)d_in[0];
    const int*   wi = (const int*)d_in[1];
    const int*   bf = (const int*)d_in[2];
    const int*   bi = (const int*)d_in[3];
    const float* W1 = (const float*)d_in[4];
    const float* b1 = (const float*)d_in[5];
    const float* W2 = (const float*)d_in[6];
    const float* b2 = (const float*)d_in[7];
    const float* W3 = (const float*)d_in[8];
    const float* b3 = (const float*)d_in[9];
    float* out = (float*)d_out;

    char* ws = (char*)d_ws;
    __half*  W1Th   = (__half*)ws;                      // 769*64*2 = 98,432 B
    __half2* W2T    = (__half2*)(ws + 98560);           // 8,192 B
    int*     wstart = (int*)(ws + 106752);              // 65,540 B
    int*     bstart = (int*)(ws + 172544);              // 65,540 B

    k_prep <<<141, 256, 0, stream>>>(W1, W2, wi, bi, W1Th, W2T, wstart, bstart);
    k_fused<<<NPOS / 4, 256, 0, stream>>>(wf, bf, (const uint2*)W1Th, W2T,
                                          wstart, bstart, (const float4*)b1,
                                          b2, W3, b3, out);
}

// Round 5
// 26.655 us; speedup vs baseline: 1.2766x; 1.2766x over previous
//
#include <hip/hip_runtime.h>
#include <hip/hip_fp16.h>
#include <math.h>

#define NPOS 16384
#define NTOT 491520
#define NFEAT 768
#define DUMMY 768          // zero row appended to W1T
#define PITCH 68           // halves per W1T row: 136B -> 8B-aligned, bank-friendly

typedef _Float16 h2 __attribute__((ext_vector_type(2)));

__device__ __forceinline__ int imin(int a, int b) { return a < b ? a : b; }
__device__ __forceinline__ float clamp01(float x) { return fminf(fmaxf(x, 0.f), 1.f); }

#if __has_builtin(__builtin_amdgcn_fdot2)
#define FDOT2(a, b, c) __builtin_amdgcn_fdot2((a), (b), (c), false)
#else
#define FDOT2(a, b, c) ((c) + (float)(a)[0] * (float)(b)[0] + (float)(a)[1] * (float)(b)[1])
#endif

__device__ __forceinline__ h2 toh2(__half2 x) { return __builtin_bit_cast(h2, x); }

// ---------------- single fused kernel ----------------
// 256 blocks (1/CU) x 1024 threads (16 waves), ~121.5KB LDS -> 1 block/CU.
// Phase A: waves 0-13 stage W1 -> LDS fp16 [769][PITCH] (transposed);
//          waves 14/15 binary-search the block's 65 white/black segment
//          boundaries; W2 -> LDS half2 [64][32]. One __syncthreads.
// Phase B: wave w handles positions p0 + w + 16*it, it=0..3:
//          gather rows from LDS (4 lane-groups, ds_read_b64, dummy-padded),
//          xor-reduce, bias+hardtanh+pack to LDS, head with W2T in VGPRs.
__global__ __launch_bounds__(1024, 4) void k_all(
    const int* __restrict__ wf, const int* __restrict__ bf,
    const int* __restrict__ wi, const int* __restrict__ bi,
    const float* __restrict__ W1, const float4* __restrict__ b1q,
    const float* __restrict__ W2, const float* __restrict__ b2,
    const float* __restrict__ W3, const float* __restrict__ b3,
    float* __restrict__ out)
{
    __shared__ __half  w1t[769 * PITCH];   // 104,584 B
    __shared__ __half2 w2t[2048];          // [i-pair 0..63][j 0..31], 8,192 B
    __shared__ int     ivs[16][64];        // per-wave index window, 4,096 B
    __shared__ uint4   a1sq[16][16];       // per-wave a1 row (128 halfs), 4,096 B
    __shared__ int     sb[2][65];          // segment boundaries, 520 B

    int t = threadIdx.x;
    int wave = t >> 6, lane = t & 63;
    int p0 = blockIdx.x * 64;

    // ---- Phase A ----
    if (wave < 14) {
        // W1 [64][768] f32 -> w1t [f][r] fp16, pitch 68. Wave-uniform row f per
        // instruction: 64 contiguous b16 writes = conflict-free. Reads are
        // 64-line strided but L1-amortized across waves.
        int r = lane;
        for (int i = 0; ; ++i) {
            int f4 = wave + 14 * i;              // float4 column group 0..191
            if (f4 >= 192) break;
            float4 v = *(const float4*)&W1[r * NFEAT + f4 * 4];
            int fb = f4 * 4;
            w1t[(fb + 0) * PITCH + r] = __float2half(v.x);
            w1t[(fb + 1) * PITCH + r] = __float2half(v.y);
            w1t[(fb + 2) * PITCH + r] = __float2half(v.z);
            w1t[(fb + 3) * PITCH + r] = __float2half(v.w);
        }
        // W2 [32][128] f32 -> w2t[i*32+j] = (W2[j][2i], W2[j][2i+1])
        for (int x = t; x < 2048; x += 896) {
            int i = x >> 5, j = x & 31;
            w2t[x] = __floats2half2_rn(W2[j * 128 + 2 * i], W2[j * 128 + 2 * i + 1]);
        }
        if (t < 64) w1t[DUMMY * PITCH + t] = __float2half(0.f);
    } else {
        // Boundary searches: wave 14 -> white, wave 15 -> black.
        // Lane l: lower_bound(arr, p0+l); all lanes also run the p0+64 chain
        // (interleaved, same wall latency), lane 63 stores it.
        const int* arr = (wave == 14) ? wi : bi;
        int col = wave - 14;
        int tgt1 = p0 + lane, tgt2 = p0 + 64;
        int lo1 = 0, hi1 = NTOT, lo2 = 0, hi2 = NTOT;
        while (lo1 < hi1 || lo2 < hi2) {
            if (lo1 < hi1) {
                int m = (lo1 + hi1) >> 1;
                if (arr[m] < tgt1) lo1 = m + 1; else hi1 = m;
            }
            if (lo2 < hi2) {
                int m = (lo2 + hi2) >> 1;
                if (arr[m] < tgt2) lo2 = m + 1; else hi2 = m;
            }
        }
        sb[col][lane] = lo1;
        if (lane == 63) sb[col][64] = lo2;
    }
    __syncthreads();

    // ---- Phase B ----
    int g = lane >> 4, k = lane & 15;
    int j = lane & 31, h = lane >> 5;

    // W2T slice for this lane's (j,h) into 32 VGPRs, reused for all 4 positions
    h2 w2r[32];
#pragma unroll
    for (int i = 0; i < 32; ++i) w2r[i] = toh2(w2t[(h * 32 + i) * 32 + j]);

    float4 bb = b1q[k];
    float b2j = b2[j], w3j = W3[j], b30 = b3[0];

    int* myiv = &ivs[wave][0];
    __half2* a1h = (__half2*)&a1sq[wave][0];

    for (int it = 0; it < 4; ++it) {
        int pl = wave + 16 * it;              // local position 0..63
        int pos = p0 + pl;
        int ws_ = sb[0][pl], we = sb[0][pl + 1];
        int bs_ = sb[1][pl], be = sb[1][pl + 1];

        float wa0 = 0.f, wa1 = 0.f, wa2 = 0.f, wa3 = 0.f;
        float ba0 = 0.f, ba1 = 0.f, ba2 = 0.f, ba3 = 0.f;

        auto run = [&](const int* __restrict__ feats, int s, int e,
                       float& A0, float& A1, float& A2, float& A3) {
            for (int tt = s; tt < e; tt += 64) {
                myiv[lane] = (tt + lane < e) ? feats[tt + lane] : DUMMY;
                int nc = (imin(e - tt, 64) + 15) >> 4;    // 16-row chunks
                for (int c = 0; c < nc; ++c) {
                    int base = c * 16 + g;
                    int f0 = myiv[base];
                    int f1 = myiv[base + 4];
                    int f2 = myiv[base + 8];
                    int f3 = myiv[base + 12];
                    uint2 d0 = *(const uint2*)&w1t[f0 * PITCH + k * 4];
                    uint2 d1 = *(const uint2*)&w1t[f1 * PITCH + k * 4];
                    uint2 d2 = *(const uint2*)&w1t[f2 * PITCH + k * 4];
                    uint2 d3 = *(const uint2*)&w1t[f3 * PITCH + k * 4];
                    h2 l0 = __builtin_bit_cast(h2, d0.x), u0 = __builtin_bit_cast(h2, d0.y);
                    h2 l1 = __builtin_bit_cast(h2, d1.x), u1 = __builtin_bit_cast(h2, d1.y);
                    h2 l2 = __builtin_bit_cast(h2, d2.x), u2 = __builtin_bit_cast(h2, d2.y);
                    h2 l3 = __builtin_bit_cast(h2, d3.x), u3 = __builtin_bit_cast(h2, d3.y);
                    A0 += (float)l0[0] + (float)l1[0] + (float)l2[0] + (float)l3[0];
                    A1 += (float)l0[1] + (float)l1[1] + (float)l2[1] + (float)l3[1];
                    A2 += (float)u0[0] + (float)u1[0] + (float)u2[0] + (float)u3[0];
                    A3 += (float)u0[1] + (float)u1[1] + (float)u2[1] + (float)u3[1];
                }
            }
        };
        run(wf, ws_, we, wa0, wa1, wa2, wa3);
        run(bf, bs_, be, ba0, ba1, ba2, ba3);

        wa0 += __shfl_xor(wa0, 16); wa0 += __shfl_xor(wa0, 32);
        wa1 += __shfl_xor(wa1, 16); wa1 += __shfl_xor(wa1, 32);
        wa2 += __shfl_xor(wa2, 16); wa2 += __shfl_xor(wa2, 32);
        wa3 += __shfl_xor(wa3, 16); wa3 += __shfl_xor(wa3, 32);
        ba0 += __shfl_xor(ba0, 16); ba0 += __shfl_xor(ba0, 32);
        ba1 += __shfl_xor(ba1, 16); ba1 += __shfl_xor(ba1, 32);
        ba2 += __shfl_xor(ba2, 16); ba2 += __shfl_xor(ba2, 32);
        ba3 += __shfl_xor(ba3, 16); ba3 += __shfl_xor(ba3, 32);

        if (lane < 32) {
            __half2 q0, q1;
            if (g == 0) {
                q0 = __floats2half2_rn(clamp01(wa0 + bb.x), clamp01(wa1 + bb.y));
                q1 = __floats2half2_rn(clamp01(wa2 + bb.z), clamp01(wa3 + bb.w));
            } else {
                q0 = __floats2half2_rn(clamp01(ba0 + bb.x), clamp01(ba1 + bb.y));
                q1 = __floats2half2_rn(clamp01(ba2 + bb.z), clamp01(ba3 + bb.w));
            }
            a1h[g * 32 + k * 2]     = q0;     // white pairs in [0..31], black [32..63]
            a1h[g * 32 + k * 2 + 1] = q1;
        }
        // same-wave LDS write->read: compiler-inserted lgkmcnt ordering

        // head: lane (j,h): dot of half h (32 half2, b128 reads) with w2r
        const uint4* aq = &a1sq[wave][h * 8];
        float acc = 0.f;
#pragma unroll
        for (int q4 = 0; q4 < 8; ++q4) {
            uint4 qq = aq[q4];
            acc = FDOT2(__builtin_bit_cast(h2, qq.x), w2r[q4 * 4 + 0], acc);
            acc = FDOT2(__builtin_bit_cast(h2, qq.y), w2r[q4 * 4 + 1], acc);
            acc = FDOT2(__builtin_bit_cast(h2, qq.z), w2r[q4 * 4 + 2], acc);
            acc = FDOT2(__builtin_bit_cast(h2, qq.w), w2r[q4 * 4 + 3], acc);
        }
        acc += __shfl_xor(acc, 32);

        float a2v = clamp01(acc + b2j);
        float p = a2v * w3j;
        p += __shfl_xor(p, 16);
        p += __shfl_xor(p, 8);
        p += __shfl_xor(p, 4);
        p += __shfl_xor(p, 2);
        p += __shfl_xor(p, 1);
        if (lane == 0)
            out[pos] = 1.f / (1.f + __expf(-(p + b30)));
    }
}

extern "C" void kernel_launch(void* const* d_in, const int* in_sizes, int n_in,
                              void* d_out, int out_size, void* d_ws, size_t ws_size,
                              hipStream_t stream) {
    const int*   wf = (const int*)d_in[0];
    const int*   wi = (const int*)d_in[1];
    const int*   bf = (const int*)d_in[2];
    const int*   bi = (const int*)d_in[3];
    const float* W1 = (const float*)d_in[4];
    const float* b1 = (const float*)d_in[5];
    const float* W2 = (const float*)d_in[6];
    const float* b2 = (const float*)d_in[7];
    const float* W3 = (const float*)d_in[8];
    const float* b3 = (const float*)d_in[9];
    float* out = (float*)d_out;

    k_all<<<NPOS / 64, 1024, 0, stream>>>(wf, bf, wi, bi, W1, (const float4*)b1,
                                          W2, b2, W3, b3, out);
}